// Round 2
// baseline (1726.547 us; speedup 1.0000x reference)
//
#include <hip/hip_runtime.h>
#include <cstdint>
#include <cstddef>

typedef _Float16 f16;
typedef _Float16 f16x8 __attribute__((ext_vector_type(8)));
typedef _Float16 f16x4 __attribute__((ext_vector_type(4)));
typedef float    f32x4 __attribute__((ext_vector_type(4)));

constexpr int S_ = 512, D_ = 2048, H_ = 32, HD_ = 64, I_ = 8192;
constexpr int M_ = 4096;  // B*S

enum { OP_F32 = 0, OP_F16 = 1, OP_SILU = 2, OP_QKT = 3, OP_PV = 4, OP_VT = 5 };

__device__ __forceinline__ void gl_lds16(const void* g, void* lds) {
  __builtin_amdgcn_global_load_lds(
      (const __attribute__((address_space(1))) void*)g,
      (__attribute__((address_space(3))) void*)lds, 16, 0, 0);
}

// C = A @ B. A is f16 M x K row-major (global_load_lds staging).
// BF32=false: B passed transposed, f16 N x K row-major (global_load_lds).
// BF32=true : B passed natural fp32 K x N row-major; staged with in-register
//             convert + LDS transpose (XOR swizzle on k keeps b128 reads aligned).
template <int BM, int BN, int WR, int WC, int OP, bool BF32>
__global__ __launch_bounds__(256, 2) void gemm_k(
    const f16* __restrict__ A, int lda,
    const void* __restrict__ Bv, int ldb,
    void* __restrict__ Cp, int ldc,
    int K, int bh0, const float* __restrict__ relmean) {
  static_assert(!BF32 || BN == 128, "BF32 staging assumes BN==128");
  constexpr int BK = 32;
  constexpr int WM = BM / WR, WN = BN / WC;
  constexpr int IM = WM / 16, IN = WN / 16;
  constexpr int CA = BM / 64, CB = BN / 64;
  __shared__ __align__(16) f16 As[BM * BK];
  __shared__ __align__(16) f16 Bs[BN * BK];
  const int tid = threadIdx.x, wave = tid >> 6, lane = tid & 63;
  const int wm = wave / WC, wn = wave % WC;
  const int bn = blockIdx.x, bm = blockIdx.y, bz = blockIdx.z;

  long aoff = 0, boff = 0;
  if constexpr (OP == OP_QKT) {
    int bh = bh0 + bz;
    long hb = (long)(bh >> 5) * (S_ * D_) + (long)(bh & (H_ - 1)) * HD_;
    aoff = hb; boff = hb;
  }
  if constexpr (OP == OP_PV) {
    int bh = bh0 + bz;
    aoff = (long)bz * S_ * S_;       // attn probs, chunk-local
    boff = (long)bh * HD_ * S_;      // vT global
  }

  const f16* Ab = A + aoff + (long)bm * BM * lda;
  const f16* Bb = BF32 ? nullptr : ((const f16*)Bv + boff + (long)bn * BN * ldb);
  const float* Bf = BF32 ? ((const float*)Bv + (long)bn * BN) : nullptr;

  f32x4 acc[IM][IN];
#pragma unroll
  for (int i = 0; i < IM; i++)
#pragma unroll
    for (int j = 0; j < IN; j++) acc[i][j] = {0.f, 0.f, 0.f, 0.f};

  const int lr = lane >> 2, l4 = lane & 3;   // A/B-NT staging: 4x16B per 32-elem row
  const int q8 = (lane >> 4) * 8, l15 = lane & 15;
  const int ng = tid & 31, kg = tid >> 5;    // BF32 staging mapping

  for (int kt = 0; kt < K; kt += BK) {
#pragma unroll
    for (int c = 0; c < CA; c++) {
      int reg = wave * CA + c;               // wave-uniform region id
      int row = reg * 16 + lr;
      gl_lds16(Ab + (long)row * lda + kt + l4 * 8, &As[reg * 512]);
    }
    if constexpr (!BF32) {
#pragma unroll
      for (int c = 0; c < CB; c++) {
        int reg = wave * CB + c;
        int row = reg * 16 + lr;
        gl_lds16(Bb + (long)row * ldb + kt + l4 * 8, &Bs[reg * 512]);
      }
    } else {
      // load 32 x 128 fp32 tile of B (K x N), convert, transpose into Bs[n][k]
      f32x4 v[4];
#pragma unroll
      for (int i = 0; i < 4; i++)
        v[i] = *(const f32x4*)&Bf[(long)(kt + kg * 4 + i) * ldb + ng * 4];
#pragma unroll
      for (int j = 0; j < 4; j++) {
        int n = ng * 4 + j;
        f16x4 w = {(f16)v[0][j], (f16)v[1][j], (f16)v[2][j], (f16)v[3][j]};
        *(f16x4*)&Bs[n * BK + ((kg * 4) ^ ((ng & 3) * 8))] = w;
      }
    }
    __syncthreads();
    f16x8 af[IM], bfr[IN];
#pragma unroll
    for (int i = 0; i < IM; i++)
      af[i] = *(const f16x8*)&As[(wm * WM + i * 16 + l15) * BK + q8];
#pragma unroll
    for (int j = 0; j < IN; j++) {
      int colL = wn * WN + j * 16 + l15;
      int koff = BF32 ? (q8 ^ (((colL >> 2) & 3) * 8)) : q8;
      bfr[j] = *(const f16x8*)&Bs[colL * BK + koff];
    }
#pragma unroll
    for (int i = 0; i < IM; i++)
#pragma unroll
      for (int j = 0; j < IN; j++)
        acc[i][j] = __builtin_amdgcn_mfma_f32_16x16x32_f16(af[i], bfr[j], acc[i][j], 0, 0, 0);
    __syncthreads();
  }

  // Epilogue. C/D layout: col = lane&15, row = (lane>>4)*4 + reg  [m89/m91]
  const int r0 = bm * BM + wm * WM + (lane >> 4) * 4;
  const int c0 = bn * BN + wn * WN + l15;
#pragma unroll
  for (int i = 0; i < IM; i++) {
#pragma unroll
    for (int j = 0; j < IN; j++) {
      int rowb = r0 + i * 16;
      int col = c0 + j * 16;
      if constexpr (OP == OP_F32) {
        float* C = (float*)Cp;
#pragma unroll
        for (int t = 0; t < 4; t++) C[(long)(rowb + t) * ldc + col] = acc[i][j][t];
      } else if constexpr (OP == OP_F16) {
        f16* C = (f16*)Cp;
#pragma unroll
        for (int t = 0; t < 4; t++) C[(long)(rowb + t) * ldc + col] = (f16)acc[i][j][t];
      } else if constexpr (OP == OP_SILU) {
        f16* C = (f16*)Cp;
#pragma unroll
        for (int t = 0; t < 4; t++) {
          float v = acc[i][j][t];
          C[(long)(rowb + t) * ldc + col] = (f16)(v / (1.f + __expf(-v)));
        }
      } else if constexpr (OP == OP_QKT) {
        f16* C = (f16*)Cp + (long)bz * S_ * S_;
#pragma unroll
        for (int t = 0; t < 4; t++) {
          int r = rowb + t;
          C[(long)r * S_ + col] = (f16)(acc[i][j][t] * 0.125f + relmean[col - r + 511]);
        }
      } else if constexpr (OP == OP_PV) {
        int bh = bh0 + bz;
        f16* C = (f16*)Cp + (long)(bh >> 5) * (S_ * D_) + (long)(bh & (H_ - 1)) * HD_;
#pragma unroll
        for (int t = 0; t < 4; t++) C[(long)(rowb + t) * ldc + col] = (f16)acc[i][j][t];
      } else if constexpr (OP == OP_VT) {
        // V output written transposed: vT[(b*H+h)*HD+hd][s]; 4 consecutive s packed
        f16* C = (f16*)Cp;
        int b = rowb >> 9, s0 = rowb & 511, h = col >> 6, hd = col & 63;
        f16x4 pk;
#pragma unroll
        for (int t = 0; t < 4; t++) pk[t] = (f16)acc[i][j][t];
        *(f16x4*)&C[((long)(b * H_ + h) * HD_ + hd) * S_ + s0] = pk;
      }
    }
  }
}

__global__ void cvt_f16_k(const float* __restrict__ in, f16* __restrict__ out, int n4) {
  int i = blockIdx.x * 256 + threadIdx.x;
  if (i >= n4) return;
  f32x4 v = ((const f32x4*)in)[i];
  f16x4 o;
#pragma unroll
  for (int t = 0; t < 4; t++) o[t] = (f16)v[t];
  ((f16x4*)out)[i] = o;
}

__global__ void relmean_k(const float* __restrict__ rel, float* __restrict__ rm) {
  int i = blockIdx.x * 256 + threadIdx.x;
  if (i >= 1023) return;
  float s = 0.f;
#pragma unroll 8
  for (int d = 0; d < 64; d++) s += rel[i * 64 + d];
  rm[i] = s * (1.f / 64.f);
}

// in-place row softmax over S_=512 f16 entries, one wave per row
__global__ __launch_bounds__(256) void softmax_k(f16* __restrict__ Sc) {
  int r = blockIdx.x * 4 + (threadIdx.x >> 6);
  int lane = threadIdx.x & 63;
  f16* s = Sc + (long)r * S_;
  float v[8], mx = -1e30f;
#pragma unroll
  for (int i = 0; i < 8; i++) { v[i] = (float)s[lane + i * 64]; mx = fmaxf(mx, v[i]); }
  for (int off = 32; off; off >>= 1) mx = fmaxf(mx, __shfl_xor(mx, off));
  float sum = 0.f;
#pragma unroll
  for (int i = 0; i < 8; i++) { v[i] = __expf(v[i] - mx); sum += v[i]; }
  for (int off = 32; off; off >>= 1) sum += __shfl_xor(sum, off);
  float rs = 1.f / sum;
#pragma unroll
  for (int i = 0; i < 8; i++) s[lane + i * 64] = (f16)(v[i] * rs);
}

__global__ void gu_k(f16* __restrict__ g, const f16* __restrict__ u, int n4) {
  int i = blockIdx.x * 256 + threadIdx.x;
  if (i >= n4) return;
  f16x4 a = ((f16x4*)g)[i], b = ((const f16x4*)u)[i];
  f16x4 o;
#pragma unroll
  for (int t = 0; t < 4; t++) o[t] = (f16)((float)a[t] * (float)b[t]);
  ((f16x4*)g)[i] = o;
}

// out = LN(X + Y) * g + b ; optional f16 copy
__global__ __launch_bounds__(256) void ln_k(const float* __restrict__ X,
                                            const float* __restrict__ Y,
                                            const float* __restrict__ g,
                                            const float* __restrict__ b,
                                            float* __restrict__ outF,
                                            f16* __restrict__ outH) {
  int row = blockIdx.x;
  const float* x = X + (long)row * D_;
  const float* y = Y + (long)row * D_;
  int t = threadIdx.x;
  float v[8], sum = 0.f, sq = 0.f;
#pragma unroll
  for (int i = 0; i < 8; i++) {
    int idx = t + i * 256;
    float val = x[idx] + y[idx];
    v[i] = val; sum += val; sq += val * val;
  }
  for (int off = 32; off; off >>= 1) { sum += __shfl_down(sum, off); sq += __shfl_down(sq, off); }
  __shared__ float s1[4], s2[4];
  if ((t & 63) == 0) { s1[t >> 6] = sum; s2[t >> 6] = sq; }
  __syncthreads();
  sum = s1[0] + s1[1] + s1[2] + s1[3];
  sq = s2[0] + s2[1] + s2[2] + s2[3];
  float mu = sum * (1.f / D_);
  float rstd = rsqrtf(sq * (1.f / D_) - mu * mu + 1e-6f);
#pragma unroll
  for (int i = 0; i < 8; i++) {
    int idx = t + i * 256;
    float nv = (v[i] - mu) * rstd * g[idx] + b[idx];
    outF[(long)row * D_ + idx] = nv;
    if (outH) outH[(long)row * D_ + idx] = (f16)nv;
  }
}

extern "C" void kernel_launch(void* const* d_in, const int* in_sizes, int n_in,
                              void* d_out, int out_size, void* d_ws, size_t ws_size,
                              hipStream_t stream) {
  const float* x    = (const float*)d_in[0];
  const float* wq   = (const float*)d_in[1];
  const float* wk   = (const float*)d_in[2];
  const float* wv   = (const float*)d_in[3];
  const float* wo   = (const float*)d_in[4];
  const float* rel  = (const float*)d_in[5];
  const float* ln1g = (const float*)d_in[6];
  const float* ln1b = (const float*)d_in[7];
  const float* gw   = (const float*)d_in[8];
  const float* uw   = (const float*)d_in[9];
  const float* dw   = (const float*)d_in[10];
  const float* ln2g = (const float*)d_in[11];
  const float* ln2b = (const float*)d_in[12];
  float* out = (float*)d_out;

  // compact arena: 8 x MD2 + 4KB  (~134.2 MB)
  constexpr size_t MD2 = (size_t)M_ * D_ * 2;
  if (ws_size < 8 * MD2 + 4096) return;  // workspace too small — fail loudly via absmax
  char* w = (char*)d_ws;
  f16* qb  = (f16*)(w + 0 * MD2);
  f16* kb  = (f16*)(w + 1 * MD2);
  f16* vT  = (f16*)(w + 2 * MD2);
  f16* xb  = (f16*)(w + 3 * MD2);
  f16* sc  = (f16*)(w + 4 * MD2);          // 2*MD2: f16 scores, 64 bh x 512 x 512
  f16* h1h = (f16*)(w + 6 * MD2);
  float* ffnc = (float*)(w + 7 * MD2);     // fp32 2048 x 2048 chunk
  float* relmean = (float*)(w + 8 * MD2);
  // aliases (phase-disjoint lifetimes):
  f16* ctxb = xb;                          // PV output (xb dead after QKV)
  float* attn_out = (float*)qb;            // WO output fp32 M x D (qb+kb dead after QK^T)
  float* h1 = (float*)sc;                  // LN1 output fp32 (scores dead after PV)
  f16* gc = qb;                            // FFN chunk gate, 2048 x I (spans qb+kb)
  f16* uc = vT;                            // FFN chunk up (spans vT+xb)

  // --- prep ---
  cvt_f16_k<<<M_ * D_ / 4 / 256, 256, 0, stream>>>(x, xb, M_ * D_ / 4);
  relmean_k<<<4, 256, 0, stream>>>(rel, relmean);

  // --- QKV projections (B = fp32 weights, natural layout) ---
  gemm_k<128, 128, 2, 2, OP_F16, true><<<dim3(16, 32, 1), 256, 0, stream>>>(
      xb, D_, wq, D_, qb, D_, D_, 0, nullptr);
  gemm_k<128, 128, 2, 2, OP_F16, true><<<dim3(16, 32, 1), 256, 0, stream>>>(
      xb, D_, wk, D_, kb, D_, D_, 0, nullptr);
  gemm_k<128, 128, 2, 2, OP_VT, true><<<dim3(16, 32, 1), 256, 0, stream>>>(
      xb, D_, wv, D_, vT, D_, D_, 0, nullptr);

  // --- attention, 4 chunks of 64 (b,h) pairs; scores f16, softmax in place ---
  for (int c = 0; c < 4; c++) {
    int bh0 = c * 64;
    gemm_k<128, 128, 2, 2, OP_QKT, false><<<dim3(4, 4, 64), 256, 0, stream>>>(
        qb, D_, kb, D_, sc, S_, HD_, bh0, relmean);
    softmax_k<<<64 * S_ / 4, 256, 0, stream>>>(sc);
    gemm_k<128, 64, 4, 1, OP_PV, false><<<dim3(1, 4, 64), 256, 0, stream>>>(
        sc, S_, vT, S_, ctxb, D_, S_, bh0, nullptr);
  }

  // --- output projection + LN1 ---
  gemm_k<128, 128, 2, 2, OP_F32, true><<<dim3(16, 32, 1), 256, 0, stream>>>(
      ctxb, D_, wo, D_, attn_out, D_, D_, 0, nullptr);
  ln_k<<<M_, 256, 0, stream>>>(x, attn_out, ln1g, ln1b, h1, h1h);

  // --- FFN, 2 chunks of 2048 rows ---
  for (int c = 0; c < 2; c++) {
    long off = (long)c * 2048;
    gemm_k<128, 128, 2, 2, OP_SILU, true><<<dim3(64, 16, 1), 256, 0, stream>>>(
        h1h + off * D_, D_, gw, I_, gc, I_, D_, 0, nullptr);
    gemm_k<128, 128, 2, 2, OP_F16, true><<<dim3(64, 16, 1), 256, 0, stream>>>(
        h1h + off * D_, D_, uw, I_, uc, I_, D_, 0, nullptr);
    gu_k<<<2048 * I_ / 4 / 256, 256, 0, stream>>>(gc, uc, 2048 * I_ / 4);
    gemm_k<128, 128, 2, 2, OP_F32, true><<<dim3(16, 16, 1), 256, 0, stream>>>(
        gc, I_, dw, D_, ffnc, D_, I_, 0, nullptr);
    ln_k<<<2048, 256, 0, stream>>>(h1 + off * D_, ffnc, ln2g, ln2b, out + off * D_, nullptr);
  }
}

// Round 3
// 1320.623 us; speedup vs baseline: 1.3074x; 1.3074x over previous
//
#include <hip/hip_runtime.h>
#include <cstdint>
#include <cstddef>

typedef _Float16 f16;
typedef _Float16 f16x8 __attribute__((ext_vector_type(8)));
typedef _Float16 f16x4 __attribute__((ext_vector_type(4)));
typedef _Float16 f16x2 __attribute__((ext_vector_type(2)));
typedef float    f32x4 __attribute__((ext_vector_type(4)));

constexpr int S_ = 512, D_ = 2048, H_ = 32, HD_ = 64, I_ = 8192;
constexpr int M_ = 4096;  // B*S

enum { OP_F32 = 0, OP_F16 = 1, OP_SILU = 2, OP_QKT = 3, OP_PV = 4,
       OP_QKV = 6, OP_UPG = 7, OP_RES = 8 };

__device__ __forceinline__ void gl_lds16(const void* g, void* lds) {
  __builtin_amdgcn_global_load_lds(
      (const __attribute__((address_space(1))) void*)g,
      (__attribute__((address_space(3))) void*)lds, 16, 0, 0);
}

// C = A @ B. A f16 MxK row-major (global_load_lds staging).
// BF32=false: B is f16 NxK row-major (global_load_lds).
// BF32=true : B natural fp32 KxN; in-register convert + LDS transpose with
//             XOR swizzle on the 4-elem k-granule (read side recomputes it).
template <int BM, int BN, int WR, int WC, int OP, bool BF32>
__global__ __launch_bounds__(256, 2) void gemm_k(
    const f16* __restrict__ A, int lda,
    const void* __restrict__ Bv, int ldb,
    void* __restrict__ Cp, int ldc,
    int K, int bh0, const float* __restrict__ relmean,
    const void* __restrict__ Bv2, const void* __restrict__ Bv3) {
  constexpr int BK = 32;
  constexpr int WM = BM / WR, WN = BN / WC;
  constexpr int IM = WM / 16, IN = WN / 16;
  constexpr int CA = BM / 64, CB = BN / 64;
  __shared__ __align__(16) f16 As[BM * BK];
  __shared__ __align__(16) f16 Bs[BN * BK];
  const int tid = threadIdx.x, wave = tid >> 6, lane = tid & 63;
  const int wm = wave / WC, wn = wave % WC;
  const int bn = blockIdx.x, bm = blockIdx.y, bz = blockIdx.z;

  long aoff = 0, boff = 0;
  if constexpr (OP == OP_QKT) {
    int bh = bh0 + bz;
    long hb = (long)(bh >> 5) * (S_ * D_) + (long)(bh & (H_ - 1)) * HD_;
    aoff = hb; boff = hb;
  }
  if constexpr (OP == OP_PV) {
    int bh = bh0 + bz;
    aoff = (long)bz * S_ * S_;       // attn probs, chunk-local
    boff = (long)bh * HD_ * S_;      // vT global
  }

  const f16* Ab = A + aoff + (long)bm * BM * lda;
  const f16* Bb = nullptr;
  const float* Bf = nullptr;
  if constexpr (BF32) {
    const float* base = (const float*)Bv;
    if constexpr (OP == OP_QKV)
      base = (bz == 0) ? (const float*)Bv : (bz == 1) ? (const float*)Bv2
                                                      : (const float*)Bv3;
    Bf = base + (long)bn * BN;
  } else {
    Bb = (const f16*)Bv + boff + (long)bn * BN * ldb;
  }

  f32x4 acc[IM][IN];
#pragma unroll
  for (int i = 0; i < IM; i++)
#pragma unroll
    for (int j = 0; j < IN; j++) acc[i][j] = {0.f, 0.f, 0.f, 0.f};

  const int lr = lane >> 2, l4 = lane & 3;   // f16-NT staging: 4x16B per 32-row
  const int q8 = (lane >> 4) * 8, l15 = lane & 15;
  constexpr int NG = BN / 4;                 // BF32: n-granules per k-row
  constexpr int KPT = BN / 32;               // BF32: k-rows per thread (4 or 2)
  const int ng = tid & (NG - 1), kg = tid / NG;

  for (int kt = 0; kt < K; kt += BK) {
#pragma unroll
    for (int c = 0; c < CA; c++) {
      int reg = wave * CA + c;               // wave-uniform region id
      int row = reg * 16 + lr;
      gl_lds16(Ab + (long)row * lda + kt + l4 * 8, &As[reg * 512]);
    }
    if constexpr (!BF32) {
#pragma unroll
      for (int c = 0; c < CB; c++) {
        int reg = wave * CB + c;
        int row = reg * 16 + lr;
        gl_lds16(Bb + (long)row * ldb + kt + l4 * 8, &Bs[reg * 512]);
      }
    } else {
      // load BK x BN fp32 tile of B, convert, transpose into Bs[n][k]
      f32x4 v[KPT];
#pragma unroll
      for (int i2 = 0; i2 < KPT; i2++)
        v[i2] = *(const f32x4*)&Bf[(long)(kt + kg * KPT + i2) * ldb + ng * 4];
#pragma unroll
      for (int j2 = 0; j2 < 4; j2++) {
        int n = ng * 4 + j2;
        int k0 = (kg * KPT) ^ ((ng & 3) * 8);
        if constexpr (KPT == 4) {
          f16x4 w = {(f16)v[0][j2], (f16)v[1][j2], (f16)v[2][j2], (f16)v[3][j2]};
          *(f16x4*)&Bs[n * BK + k0] = w;
        } else {
          f16x2 w = {(f16)v[0][j2], (f16)v[1][j2]};
          *(f16x2*)&Bs[n * BK + k0] = w;
        }
      }
    }
    __syncthreads();
    f16x8 af[IM], bfr[IN];
#pragma unroll
    for (int i = 0; i < IM; i++)
      af[i] = *(const f16x8*)&As[(wm * WM + i * 16 + l15) * BK + q8];
#pragma unroll
    for (int j = 0; j < IN; j++) {
      int colL = wn * WN + j * 16 + l15;
      int koff = BF32 ? (q8 ^ (((colL >> 2) & 3) * 8)) : q8;
      bfr[j] = *(const f16x8*)&Bs[colL * BK + koff];
    }
#pragma unroll
    for (int i = 0; i < IM; i++)
#pragma unroll
      for (int j = 0; j < IN; j++)
        acc[i][j] = __builtin_amdgcn_mfma_f32_16x16x32_f16(af[i], bfr[j], acc[i][j], 0, 0, 0);
    __syncthreads();
  }

  // Epilogue. C/D layout: col = lane&15, row = (lane>>4)*4 + reg  [m89/m91]
  const int r0 = bm * BM + wm * WM + (lane >> 4) * 4;
  const int c0 = bn * BN + wn * WN + l15;
#pragma unroll
  for (int i = 0; i < IM; i++) {
#pragma unroll
    for (int j = 0; j < IN; j++) {
      int rowb = r0 + i * 16;
      int col = c0 + j * 16;
      if constexpr (OP == OP_F32) {
        float* C = (float*)Cp;
#pragma unroll
        for (int t = 0; t < 4; t++) C[(long)(rowb + t) * ldc + col] = acc[i][j][t];
      } else if constexpr (OP == OP_F16) {
        f16* C = (f16*)Cp;
#pragma unroll
        for (int t = 0; t < 4; t++) C[(long)(rowb + t) * ldc + col] = (f16)acc[i][j][t];
      } else if constexpr (OP == OP_SILU) {
        f16* C = (f16*)Cp;
#pragma unroll
        for (int t = 0; t < 4; t++) {
          float v = acc[i][j][t];
          C[(long)(rowb + t) * ldc + col] = (f16)(v / (1.f + __expf(-v)));
        }
      } else if constexpr (OP == OP_UPG) {
        // fused: out = silu(gate) * up, in place over the gate buffer
        f16* C = (f16*)Cp;
        const f16* G = (const f16*)Bv2;
#pragma unroll
        for (int t = 0; t < 4; t++) {
          long idx = (long)(rowb + t) * ldc + col;
          C[idx] = (f16)((float)G[idx] * acc[i][j][t]);
        }
      } else if constexpr (OP == OP_RES) {
        // fused residual: out_f16 = acc + h1 (LN2 input)
        f16* C = (f16*)Cp;
#pragma unroll
        for (int t = 0; t < 4; t++) {
          long idx = (long)(rowb + t) * ldc + col;
          C[idx] = (f16)(acc[i][j][t] + relmean[idx]);
        }
      } else if constexpr (OP == OP_QKT) {
        f16* C = (f16*)Cp + (long)bz * S_ * S_;
#pragma unroll
        for (int t = 0; t < 4; t++) {
          int r = rowb + t;
          C[(long)r * S_ + col] = (f16)(acc[i][j][t] * 0.125f + relmean[col - r + 511]);
        }
      } else if constexpr (OP == OP_PV) {
        int bh = bh0 + bz;
        f16* C = (f16*)Cp + (long)(bh >> 5) * (S_ * D_) + (long)(bh & (H_ - 1)) * HD_;
#pragma unroll
        for (int t = 0; t < 4; t++) C[(long)(rowb + t) * ldc + col] = (f16)acc[i][j][t];
      } else if constexpr (OP == OP_QKV) {
        f16* C = (f16*)Cp;
        if (bz < 2) {  // q or k: plain f16 rows
          f16* Cq = C + (long)bz * M_ * D_;
#pragma unroll
          for (int t = 0; t < 4; t++) Cq[(long)(rowb + t) * ldc + col] = (f16)acc[i][j][t];
        } else {       // v: write transposed vT[(b*H+h)*HD+hd][s]
          f16* Cv = C + (long)2 * M_ * D_;
          int b = rowb >> 9, s0 = rowb & 511, h = col >> 6, hd = col & 63;
          f16x4 pk;
#pragma unroll
          for (int t = 0; t < 4; t++) pk[t] = (f16)acc[i][j][t];
          *(f16x4*)&Cv[((long)(b * H_ + h) * HD_ + hd) * S_ + s0] = pk;
        }
      }
    }
  }
}

__global__ void cvt_f16_k(const float* __restrict__ in, f16* __restrict__ out, int n4) {
  int i = blockIdx.x * 256 + threadIdx.x;
  if (i >= n4) return;
  f32x4 v = ((const f32x4*)in)[i];
  f16x4 o;
#pragma unroll
  for (int t = 0; t < 4; t++) o[t] = (f16)v[t];
  ((f16x4*)out)[i] = o;
}

__global__ void relmean_k(const float* __restrict__ rel, float* __restrict__ rm) {
  int i = blockIdx.x * 256 + threadIdx.x;
  if (i >= 1023) return;
  float s = 0.f;
#pragma unroll 8
  for (int d = 0; d < 64; d++) s += rel[i * 64 + d];
  rm[i] = s * (1.f / 64.f);
}

// in-place row softmax over S_=512 f16, one wave per row, f16x8 vector I/O
__global__ __launch_bounds__(256) void softmax_k(f16* __restrict__ Sc) {
  int r = blockIdx.x * 4 + (threadIdx.x >> 6);
  int lane = threadIdx.x & 63;
  f16* s = Sc + (long)r * S_;
  f16x8 d = *(const f16x8*)&s[lane * 8];
  float v[8], mx = -1e30f;
#pragma unroll
  for (int i = 0; i < 8; i++) { v[i] = (float)d[i]; mx = fmaxf(mx, v[i]); }
  for (int off = 32; off; off >>= 1) mx = fmaxf(mx, __shfl_xor(mx, off));
  float sum = 0.f;
#pragma unroll
  for (int i = 0; i < 8; i++) { v[i] = __expf(v[i] - mx); sum += v[i]; }
  for (int off = 32; off; off >>= 1) sum += __shfl_xor(sum, off);
  float rs = 1.f / sum;
  f16x8 o;
#pragma unroll
  for (int i = 0; i < 8; i++) o[i] = (f16)(v[i] * rs);
  *(f16x8*)&s[lane * 8] = o;
}

// out = LN(X + Y) * g + b ; fp32 out + f16 copy
__global__ __launch_bounds__(256) void ln_k(const float* __restrict__ X,
                                            const float* __restrict__ Y,
                                            const float* __restrict__ g,
                                            const float* __restrict__ b,
                                            float* __restrict__ outF,
                                            f16* __restrict__ outH) {
  int row = blockIdx.x;
  const float* x = X + (long)row * D_;
  const float* y = Y + (long)row * D_;
  int t = threadIdx.x;
  float v[8], sum = 0.f, sq = 0.f;
#pragma unroll
  for (int i = 0; i < 8; i++) {
    int idx = t + i * 256;
    float val = x[idx] + y[idx];
    v[i] = val; sum += val; sq += val * val;
  }
  for (int off = 32; off; off >>= 1) { sum += __shfl_down(sum, off); sq += __shfl_down(sq, off); }
  __shared__ float s1[4], s2[4];
  if ((t & 63) == 0) { s1[t >> 6] = sum; s2[t >> 6] = sq; }
  __syncthreads();
  sum = s1[0] + s1[1] + s1[2] + s1[3];
  sq = s2[0] + s2[1] + s2[2] + s2[3];
  float mu = sum * (1.f / D_);
  float rstd = rsqrtf(sq * (1.f / D_) - mu * mu + 1e-6f);
#pragma unroll
  for (int i = 0; i < 8; i++) {
    int idx = t + i * 256;
    float nv = (v[i] - mu) * rstd * g[idx] + b[idx];
    outF[(long)row * D_ + idx] = nv;
    outH[(long)row * D_ + idx] = (f16)nv;
  }
}

// out = LN(X) * g + b ; X already holds (h1 + ffn) in f16
__global__ __launch_bounds__(256) void ln2s_k(const f16* __restrict__ X,
                                              const float* __restrict__ g,
                                              const float* __restrict__ b,
                                              float* __restrict__ outF) {
  int row = blockIdx.x;
  const f16* x = X + (long)row * D_;
  int t = threadIdx.x;
  float v[8], sum = 0.f, sq = 0.f;
#pragma unroll
  for (int i = 0; i < 8; i++) {
    float val = (float)x[t + i * 256];
    v[i] = val; sum += val; sq += val * val;
  }
  for (int off = 32; off; off >>= 1) { sum += __shfl_down(sum, off); sq += __shfl_down(sq, off); }
  __shared__ float s1[4], s2[4];
  if ((t & 63) == 0) { s1[t >> 6] = sum; s2[t >> 6] = sq; }
  __syncthreads();
  sum = s1[0] + s1[1] + s1[2] + s1[3];
  sq = s2[0] + s2[1] + s2[2] + s2[3];
  float mu = sum * (1.f / D_);
  float rstd = rsqrtf(sq * (1.f / D_) - mu * mu + 1e-6f);
#pragma unroll
  for (int i = 0; i < 8; i++) {
    int idx = t + i * 256;
    outF[(long)row * D_ + idx] = (v[i] - mu) * rstd * g[idx] + b[idx];
  }
}

extern "C" void kernel_launch(void* const* d_in, const int* in_sizes, int n_in,
                              void* d_out, int out_size, void* d_ws, size_t ws_size,
                              hipStream_t stream) {
  const float* x    = (const float*)d_in[0];
  const float* wq   = (const float*)d_in[1];
  const float* wk   = (const float*)d_in[2];
  const float* wv   = (const float*)d_in[3];
  const float* wo   = (const float*)d_in[4];
  const float* rel  = (const float*)d_in[5];
  const float* ln1g = (const float*)d_in[6];
  const float* ln1b = (const float*)d_in[7];
  const float* gw   = (const float*)d_in[8];
  const float* uw   = (const float*)d_in[9];
  const float* dw   = (const float*)d_in[10];
  const float* ln2g = (const float*)d_in[11];
  const float* ln2b = (const float*)d_in[12];
  float* out = (float*)d_out;

  // arena: 8 x MD2 + 4KB (~134.2 MB)
  constexpr size_t MD2 = (size_t)M_ * D_ * 2;
  if (ws_size < 8 * MD2 + 4096) return;
  char* w = (char*)d_ws;
  f16* qb  = (f16*)(w + 0 * MD2);          // s0; qb/kb/vT contiguous for merged QKV
  f16* vT  = (f16*)(w + 2 * MD2);          // s2
  f16* xb  = (f16*)(w + 3 * MD2);          // s3
  f16* sc  = (f16*)(w + 4 * MD2);          // s4-5: f16 scores (64 bh x 512 x 512)
  f16* h1h = (f16*)(w + 6 * MD2);          // s6
  float* relmean = (float*)(w + 8 * MD2);  // 4 KB tail
  // phase-disjoint aliases:
  f16* ctxb = xb;                          // s3 (xb dead after QKV)
  float* attn_out = (float*)qb;            // s0-1 fp32 MxD (qb/kb dead after QKT)
  float* h1 = (float*)sc;                  // s4-5 fp32 (scores dead after PV)
  f16* gc = qb;                            // s0-3: full-M gate/product buffer (67 MB)
  f16* h2h = h1h;                          // s6: (h1+ffn) f16 (h1h dead after up)

  // --- prep ---
  cvt_f16_k<<<M_ * D_ / 4 / 256, 256, 0, stream>>>(x, xb, M_ * D_ / 4);
  relmean_k<<<4, 256, 0, stream>>>(rel, relmean);

  // --- QKV merged (bz: 0=q, 1=k, 2=v-transposed) ---
  gemm_k<128, 128, 2, 2, OP_QKV, true><<<dim3(16, 32, 3), 256, 0, stream>>>(
      xb, D_, wq, D_, qb, D_, D_, 0, nullptr, wk, wv);

  // --- attention, 4 chunks of 64 (b,h); f16 scores, softmax in place ---
  for (int c = 0; c < 4; c++) {
    int bh0 = c * 64;
    gemm_k<128, 128, 2, 2, OP_QKT, false><<<dim3(4, 4, 64), 256, 0, stream>>>(
        qb, D_, qb + (size_t)M_ * D_, D_, sc, S_, HD_, bh0, relmean, nullptr, nullptr);
    softmax_k<<<64 * S_ / 4, 256, 0, stream>>>(sc);
    gemm_k<64, 64, 2, 2, OP_PV, false><<<dim3(1, 8, 64), 256, 0, stream>>>(
        sc, S_, vT, S_, ctxb, D_, S_, bh0, nullptr, nullptr, nullptr);
  }

  // --- output projection (BN=64 -> 1024 blocks) + LN1 ---
  gemm_k<128, 64, 2, 2, OP_F32, true><<<dim3(32, 32, 1), 256, 0, stream>>>(
      ctxb, D_, wo, D_, attn_out, D_, D_, 0, nullptr, nullptr, nullptr);
  ln_k<<<M_, 256, 0, stream>>>(x, attn_out, ln1g, ln1b, h1, h1h);

  // --- FFN, full M ---
  gemm_k<128, 128, 2, 2, OP_SILU, true><<<dim3(64, 32, 1), 256, 0, stream>>>(
      h1h, D_, gw, I_, gc, I_, D_, 0, nullptr, nullptr, nullptr);
  gemm_k<128, 128, 2, 2, OP_UPG, true><<<dim3(64, 32, 1), 256, 0, stream>>>(
      h1h, D_, uw, I_, gc, I_, D_, 0, nullptr, gc, nullptr);
  gemm_k<128, 64, 2, 2, OP_RES, true><<<dim3(32, 32, 1), 256, 0, stream>>>(
      gc, I_, dw, D_, h2h, D_, I_, 0, h1, nullptr, nullptr);
  ln2s_k<<<M_, 256, 0, stream>>>(h2h, ln2g, ln2b, out);
}